// Round 6
// baseline (58.392 us; speedup 1.0000x reference)
//
#include <hip/hip_runtime.h>

#define NB 32
#define NT 2048
#define TOUT 512
#define ND 256
#define TILE_M 16
#define LDA 264   // ushort stride for pooled rows in LDS (256+8): 528B, breaks 16-row bank alias
#define LDH 264   // float stride for h rows

typedef __attribute__((ext_vector_type(4))) float f32x4;
typedef __attribute__((ext_vector_type(8))) short bf16x8;
typedef __attribute__((ext_vector_type(4))) unsigned short u16x4;

__device__ __forceinline__ unsigned short f2b(float f) {
    unsigned int u = __builtin_bit_cast(unsigned int, f);
    return (unsigned short)((u + 0x7FFFu + ((u >> 16) & 1u)) >> 16);  // RNE
}

__device__ __forceinline__ float gelu_exact(float x) {
    return 0.5f * x * (1.0f + erff(x * 0.70710678118654752440f));
}

template <int K>
__device__ __forceinline__ f32x4 sumK(const float* p) {
    f32x4 v[K];
    #pragma unroll
    for (int t = 0; t < K; ++t)
        v[t] = *reinterpret_cast<const f32x4*>(p + (size_t)t * ND);
    f32x4 s = v[0];
    #pragma unroll
    for (int t = 1; t < K; ++t) s += v[t];
    return s;
}

// One wave per output row j; no LDS, no barriers. Extra grid.y slice converts W.
__global__ __launch_bounds__(256, 6)
void pool_kernel(const float* __restrict__ mu,
                 const int* __restrict__ lens,
                 const int* __restrict__ olens,
                 const float* __restrict__ wf,
                 unsigned short* __restrict__ wb,
                 unsigned short* __restrict__ pooled)
{
    const int tid  = (int)threadIdx.x;
    const int lane = tid & 63;
    const int wv   = tid >> 6;

    if (blockIdx.y == TOUT / 4) {   // W f32 -> bf16: 32 blocks x 256 thr x 8 elems
        const int i = (blockIdx.x * 256 + tid) * 8;
        f32x4 a = *reinterpret_cast<const f32x4*>(wf + i);
        f32x4 c = *reinterpret_cast<const f32x4*>(wf + i + 4);
        u16x4 p0, p1;
        p0.x = f2b(a.x); p0.y = f2b(a.y); p0.z = f2b(a.z); p0.w = f2b(a.w);
        p1.x = f2b(c.x); p1.y = f2b(c.y); p1.z = f2b(c.z); p1.w = f2b(c.w);
        *reinterpret_cast<u16x4*>(wb + i)     = p0;
        *reinterpret_cast<u16x4*>(wb + i + 4) = p1;
        return;
    }

    const int b = blockIdx.x;
    const int j = blockIdx.y * 4 + wv;
    const int L = lens[b];
    const int O = olens[b];

    f32x4 s = {0.f, 0.f, 0.f, 0.f};
    if (j < O) {
        const int st  = (j * L) / O;
        const int en  = ((j + 1) * L + O - 1) / O;
        const int cnt = en - st;                 // wave-uniform, in [2, 9]
        const float* p = mu + (size_t)(b * NT + st) * ND + lane * 4;
        switch (cnt) {                           // uniform scalar branch; each case
            case 2: s = sumK<2>(p); break;       // issues exactly cnt independent loads
            case 3: s = sumK<3>(p); break;
            case 4: s = sumK<4>(p); break;
            case 5: s = sumK<5>(p); break;
            case 6: s = sumK<6>(p); break;
            case 7: s = sumK<7>(p); break;
            case 8: s = sumK<8>(p); break;
            case 9: s = sumK<9>(p); break;
            default:
                for (int t = 0; t < cnt; ++t)
                    s += *reinterpret_cast<const f32x4*>(p + (size_t)t * ND);
                break;
        }
        s *= 1.0f / (float)cnt;
    }
    u16x4 q;
    q.x = f2b(s.x); q.y = f2b(s.y); q.z = f2b(s.z); q.w = f2b(s.w);
    *reinterpret_cast<u16x4*>(pooled + ((size_t)b * TOUT + j) * ND + lane * 4) = q;
}

// GEMM + GELU + LayerNorm from the pooled bf16 buffer (L2-hot, 8 MB).
__global__ __launch_bounds__(256, 4)
void mm_kernel(const unsigned short* __restrict__ pooled,
               const unsigned short* __restrict__ wb,
               const float* __restrict__ gamma,
               const float* __restrict__ beta,
               float* __restrict__ out)
{
    __shared__ unsigned short a_lds[TILE_M * LDA];  // pooled rows, bf16
    __shared__ float h_lds[TILE_M * LDH];           // post-GELU rows, f32

    const int b    = blockIdx.x;
    const int j0   = blockIdx.y * TILE_M;
    const int tid  = (int)threadIdx.x;
    const int lane = tid & 63;
    const int wv   = tid >> 6;

    // stage 16 contiguous pooled rows (8 KB) -> LDS with padded stride
    const unsigned short* prow = pooled + ((size_t)b * TOUT + j0) * ND;
    #pragma unroll
    for (int it = 0; it < 4; ++it) {
        const int idx4 = it * 256 + tid;     // u16x4 units, 1024 total
        const int m    = idx4 >> 6;          // row 0..15
        const int dd   = (idx4 & 63) * 4;    // halfword offset
        *reinterpret_cast<u16x4*>(&a_lds[m * LDA + dd]) =
            *reinterpret_cast<const u16x4*>(prow + (size_t)idx4 * 4);
    }
    __syncthreads();

    // GEMM h[j,e] = sum_d pooled[j,d] * W[e,d] via mfma_f32_16x16x32_bf16
    const int r  = lane & 15;   // A-row / B-col within 16-tile
    const int kg = lane >> 4;   // k-group of 8
    const int e0 = wv * 64;     // wave's output-column base

    f32x4 acc[4];
    #pragma unroll
    for (int c = 0; c < 4; ++c) acc[c] = (f32x4){0.f, 0.f, 0.f, 0.f};

    #pragma unroll
    for (int kk = 0; kk < 8; ++kk) {
        const int k0 = kk * 32 + kg * 8;
        bf16x8 af = *reinterpret_cast<const bf16x8*>(&a_lds[r * LDA + k0]);
        #pragma unroll
        for (int ct = 0; ct < 4; ++ct) {
            const int e = e0 + ct * 16 + r;
            bf16x8 bfr = *reinterpret_cast<const bf16x8*>(&wb[e * ND + k0]);
            acc[ct] = __builtin_amdgcn_mfma_f32_16x16x32_bf16(af, bfr, acc[ct], 0, 0, 0);
        }
    }

    // exact GELU; C/D layout (verified m89): col = lane&15, row = (lane>>4)*4 + q
    #pragma unroll
    for (int ct = 0; ct < 4; ++ct) {
        const int col  = e0 + ct * 16 + r;
        const int row0 = kg * 4;
        #pragma unroll
        for (int q = 0; q < 4; ++q)
            h_lds[(row0 + q) * LDH + col] = gelu_exact(acc[ct][q]);
    }
    __syncthreads();

    // LayerNorm over D, coalesced store
    const f32x4 g4 = *reinterpret_cast<const f32x4*>(&gamma[lane * 4]);
    const f32x4 b4 = *reinterpret_cast<const f32x4*>(&beta[lane * 4]);
    #pragma unroll
    for (int i = 0; i < 4; ++i) {
        const int m = wv + i * 4;
        f32x4 v = *reinterpret_cast<const f32x4*>(&h_lds[m * LDH + lane * 4]);
        float s  = v.x + v.y + v.z + v.w;
        float sq = v.x * v.x + v.y * v.y + v.z * v.z + v.w * v.w;
        #pragma unroll
        for (int off = 32; off > 0; off >>= 1) {
            s  += __shfl_xor(s, off, 64);
            sq += __shfl_xor(sq, off, 64);
        }
        const float mean = s * (1.0f / 256.0f);
        const float var  = sq * (1.0f / 256.0f) - mean * mean;
        const float rs   = rsqrtf(var + 1e-5f);
        f32x4 o = (v - mean) * rs * g4 + b4;
        *reinterpret_cast<f32x4*>(&out[((size_t)(b * TOUT) + j0 + m) * ND + lane * 4]) = o;
    }
}

// Fallback (ws too small): monolithic fused kernel, dynamic pooling loop. Slow but correct.
__global__ __launch_bounds__(256, 4)
void fused_fallback(const float* __restrict__ mu,
                    const int* __restrict__ lens,
                    const int* __restrict__ olens,
                    const float* __restrict__ wf,
                    const float* __restrict__ gamma,
                    const float* __restrict__ beta,
                    float* __restrict__ out)
{
    __shared__ unsigned short a_lds[TILE_M * LDA];
    __shared__ float h_lds[TILE_M * LDH];

    const int b    = blockIdx.x;
    const int j0   = blockIdx.y * TILE_M;
    const int tid  = (int)threadIdx.x;
    const int lane = tid & 63;
    const int wv   = tid >> 6;
    const int L = lens[b];
    const int O = olens[b];

    for (int m = wv; m < TILE_M; m += 4) {
        const int j = j0 + m;
        f32x4 acc = {0.f, 0.f, 0.f, 0.f};
        if (j < O) {
            const int s = (j * L) / O;
            const int e = ((j + 1) * L + O - 1) / O;
            const float* src = mu + (size_t)(b * NT + s) * ND + lane * 4;
            for (int t = s; t < e; ++t) {
                acc += *reinterpret_cast<const f32x4*>(src);
                src += ND;
            }
            acc *= (1.0f / (float)(e - s));
        }
        u16x4 p;
        p.x = f2b(acc.x); p.y = f2b(acc.y); p.z = f2b(acc.z); p.w = f2b(acc.w);
        *reinterpret_cast<u16x4*>(&a_lds[m * LDA + lane * 4]) = p;
    }
    __syncthreads();

    const int r  = lane & 15;
    const int kg = lane >> 4;
    const int e0 = wv * 64;
    f32x4 acc[4];
    #pragma unroll
    for (int c = 0; c < 4; ++c) acc[c] = (f32x4){0.f, 0.f, 0.f, 0.f};
    #pragma unroll
    for (int kk = 0; kk < 8; ++kk) {
        const int k0 = kk * 32 + kg * 8;
        bf16x8 af = *reinterpret_cast<const bf16x8*>(&a_lds[r * LDA + k0]);
        #pragma unroll
        for (int ct = 0; ct < 4; ++ct) {
            const int e = e0 + ct * 16 + r;
            f32x4 w0 = *reinterpret_cast<const f32x4*>(&wf[e * ND + k0]);
            f32x4 w1 = *reinterpret_cast<const f32x4*>(&wf[e * ND + k0 + 4]);
            union { bf16x8 v; unsigned short u[8]; } cv;
            cv.u[0] = f2b(w0.x); cv.u[1] = f2b(w0.y);
            cv.u[2] = f2b(w0.z); cv.u[3] = f2b(w0.w);
            cv.u[4] = f2b(w1.x); cv.u[5] = f2b(w1.y);
            cv.u[6] = f2b(w1.z); cv.u[7] = f2b(w1.w);
            acc[ct] = __builtin_amdgcn_mfma_f32_16x16x32_bf16(af, cv.v, acc[ct], 0, 0, 0);
        }
    }
    #pragma unroll
    for (int ct = 0; ct < 4; ++ct) {
        const int col  = e0 + ct * 16 + r;
        const int row0 = kg * 4;
        #pragma unroll
        for (int q = 0; q < 4; ++q)
            h_lds[(row0 + q) * LDH + col] = gelu_exact(acc[ct][q]);
    }
    __syncthreads();
    const f32x4 g4 = *reinterpret_cast<const f32x4*>(&gamma[lane * 4]);
    const f32x4 b4 = *reinterpret_cast<const f32x4*>(&beta[lane * 4]);
    #pragma unroll
    for (int i = 0; i < 4; ++i) {
        const int m = wv + i * 4;
        f32x4 v = *reinterpret_cast<const f32x4*>(&h_lds[m * LDH + lane * 4]);
        float s  = v.x + v.y + v.z + v.w;
        float sq = v.x * v.x + v.y * v.y + v.z * v.z + v.w * v.w;
        #pragma unroll
        for (int off = 32; off > 0; off >>= 1) {
            s  += __shfl_xor(s, off, 64);
            sq += __shfl_xor(sq, off, 64);
        }
        const float mean = s * (1.0f / 256.0f);
        const float var  = sq * (1.0f / 256.0f) - mean * mean;
        const float rs   = rsqrtf(var + 1e-5f);
        f32x4 o = (v - mean) * rs * g4 + b4;
        *reinterpret_cast<f32x4*>(&out[((size_t)(b * TOUT) + j0 + m) * ND + lane * 4]) = o;
    }
}

extern "C" void kernel_launch(void* const* d_in, const int* in_sizes, int n_in,
                              void* d_out, int out_size, void* d_ws, size_t ws_size,
                              hipStream_t stream) {
    const float* mu    = (const float*)d_in[0];
    const int*   lens  = (const int*)d_in[1];
    const int*   olens = (const int*)d_in[2];
    const float* wf    = (const float*)d_in[3];
    const float* gamma = (const float*)d_in[4];
    const float* beta  = (const float*)d_in[5];
    float* out = (float*)d_out;

    const size_t wb_elems = (size_t)ND * ND;                       // 64 Ki bf16
    const size_t pooled_elems = (size_t)NB * TOUT * ND;            // 4 Mi bf16
    const size_t need = (wb_elems + pooled_elems) * sizeof(unsigned short);

    if (ws_size >= need) {
        unsigned short* wb     = (unsigned short*)d_ws;
        unsigned short* pooled = wb + wb_elems;
        // ATTRIBUTION PROBE (this round only): pool launched 3x (idempotent,
        // deterministic -> graph-legal). dur_R6 = 3P + M; with R5's P + M = 37.1,
        // P = (dur_R6 - 37.1) / 2. Decides pool-wall (H1) vs W-gather-wall (H2).
        pool_kernel<<<dim3(NB, TOUT / 4 + 1), dim3(256), 0, stream>>>(
            mu, lens, olens, wf, wb, pooled);
        pool_kernel<<<dim3(NB, TOUT / 4 + 1), dim3(256), 0, stream>>>(
            mu, lens, olens, wf, wb, pooled);
        pool_kernel<<<dim3(NB, TOUT / 4 + 1), dim3(256), 0, stream>>>(
            mu, lens, olens, wf, wb, pooled);
        mm_kernel<<<dim3(NB, TOUT / TILE_M), dim3(256), 0, stream>>>(
            pooled, wb, gamma, beta, out);
    } else {
        fused_fallback<<<dim3(NB, TOUT / TILE_M), dim3(256), 0, stream>>>(
            mu, lens, olens, wf, gamma, beta, out);
    }
}

// Round 7
// 28.953 us; speedup vs baseline: 2.0168x; 2.0168x over previous
//
#include <hip/hip_runtime.h>

#define NB 32
#define NT 2048
#define TOUT 512
#define ND 256
#define TILE_M 16
#define BLK_J 64  // j-rows per mm block (4 j-tiles of 16)
#define LDA 264   // ushort stride for pooled rows in LDS (256+8): 528B, 16B-aligned
#define LDH 264   // float stride for h rows

typedef __attribute__((ext_vector_type(4))) float f32x4;
typedef __attribute__((ext_vector_type(8))) short bf16x8;
typedef __attribute__((ext_vector_type(4))) unsigned short u16x4;

__device__ __forceinline__ unsigned short f2b(float f) {
    unsigned int u = __builtin_bit_cast(unsigned int, f);
    return (unsigned short)((u + 0x7FFFu + ((u >> 16) & 1u)) >> 16);  // RNE
}

__device__ __forceinline__ float gelu_exact(float x) {
    return 0.5f * x * (1.0f + erff(x * 0.70710678118654752440f));
}

template <int K>
__device__ __forceinline__ f32x4 sumK(const float* p) {
    f32x4 v[K];
    #pragma unroll
    for (int t = 0; t < K; ++t)
        v[t] = *reinterpret_cast<const f32x4*>(p + (size_t)t * ND);
    f32x4 s = v[0];
    #pragma unroll
    for (int t = 1; t < K; ++t) s += v[t];
    return s;
}

// One wave per output row j; no LDS, no barriers. Extra grid.y slice converts W
// into FRAGMENT-MAJOR layout: wbF[((et*8+kk)*64 + lane)*8 + i] =
//   W[e = et*16 + (lane&15)][k = kk*32 + (lane>>4)*8 + i]
// so mm's B-fragment loads are lane-contiguous 1KB coalesced reads.
__global__ __launch_bounds__(256, 6)
void pool_kernel(const float* __restrict__ mu,
                 const int* __restrict__ lens,
                 const int* __restrict__ olens,
                 const float* __restrict__ wf,
                 unsigned short* __restrict__ wbF,
                 unsigned short* __restrict__ pooled)
{
    const int tid  = (int)threadIdx.x;
    const int lane = tid & 63;
    const int wv   = tid >> 6;

    if (blockIdx.y == TOUT / 4) {   // W f32 -> bf16 fragment-major (8192 threads)
        const int gid = blockIdx.x * 256 + tid;
        const int l   = gid & 63;
        const int kk  = (gid >> 6) & 7;
        const int et  = gid >> 9;                 // 0..15
        const int e   = et * 16 + (l & 15);
        const int k   = kk * 32 + (l >> 4) * 8;
        f32x4 a = *reinterpret_cast<const f32x4*>(wf + e * ND + k);
        f32x4 c = *reinterpret_cast<const f32x4*>(wf + e * ND + k + 4);
        u16x4 p0, p1;
        p0.x = f2b(a.x); p0.y = f2b(a.y); p0.z = f2b(a.z); p0.w = f2b(a.w);
        p1.x = f2b(c.x); p1.y = f2b(c.y); p1.z = f2b(c.z); p1.w = f2b(c.w);
        *reinterpret_cast<u16x4*>(wbF + (size_t)gid * 8)     = p0;
        *reinterpret_cast<u16x4*>(wbF + (size_t)gid * 8 + 4) = p1;
        return;
    }

    const int b = blockIdx.x;
    const int j = blockIdx.y * 4 + wv;
    const int L = lens[b];
    const int O = olens[b];

    f32x4 s = {0.f, 0.f, 0.f, 0.f};
    if (j < O) {
        const int st  = (j * L) / O;
        const int en  = ((j + 1) * L + O - 1) / O;
        const int cnt = en - st;                 // wave-uniform, in [2, 9]
        const float* p = mu + (size_t)(b * NT + st) * ND + lane * 4;
        switch (cnt) {                           // uniform scalar branch; each case
            case 2: s = sumK<2>(p); break;       // issues exactly cnt independent loads
            case 3: s = sumK<3>(p); break;
            case 4: s = sumK<4>(p); break;
            case 5: s = sumK<5>(p); break;
            case 6: s = sumK<6>(p); break;
            case 7: s = sumK<7>(p); break;
            case 8: s = sumK<8>(p); break;
            case 9: s = sumK<9>(p); break;
            default:
                for (int t = 0; t < cnt; ++t)
                    s += *reinterpret_cast<const f32x4*>(p + (size_t)t * ND);
                break;
        }
        s *= 1.0f / (float)cnt;
    }
    u16x4 q;
    q.x = f2b(s.x); q.y = f2b(s.y); q.z = f2b(s.z); q.w = f2b(s.w);
    *reinterpret_cast<u16x4*>(pooled + ((size_t)b * TOUT + j) * ND + lane * 4) = q;
}

// GEMM + GELU + LayerNorm. W is REGISTER-RESIDENT per wave (64 VGPRs),
// loaded once per block from fragment-major wbF; 4 j-tiles amortize it.
__global__ __launch_bounds__(512, 2)
void mm_kernel(const unsigned short* __restrict__ pooled,
               const unsigned short* __restrict__ wbF,
               const float* __restrict__ gamma,
               const float* __restrict__ beta,
               float* __restrict__ out)
{
    __shared__ unsigned short a_lds[TILE_M * LDA];  // pooled rows, bf16
    __shared__ float h_lds[TILE_M * LDH];           // post-GELU rows, f32

    const int b    = blockIdx.x;
    const int jb   = blockIdx.y * BLK_J;
    const int tid  = (int)threadIdx.x;
    const int lane = tid & 63;
    const int wv   = tid >> 6;     // 0..7, e-range [wv*32, wv*32+32)
    const int r    = lane & 15;
    const int kg   = lane >> 4;

    // ---- W fragments -> registers (once per block; coalesced 1KB loads) ----
    bf16x8 wreg[8][2];
    #pragma unroll
    for (int kk = 0; kk < 8; ++kk)
        #pragma unroll
        for (int p = 0; p < 2; ++p) {
            const int et = wv * 2 + p;
            wreg[kk][p] = *reinterpret_cast<const bf16x8*>(
                wbF + (size_t)((et * 8 + kk) * 64 + lane) * 8);
        }

    const f32x4 g4 = *reinterpret_cast<const f32x4*>(&gamma[lane * 4]);
    const f32x4 b4 = *reinterpret_cast<const f32x4*>(&beta[lane * 4]);

    for (int jt = 0; jt < BLK_J / TILE_M; ++jt) {
        const int j0 = jb + jt * TILE_M;

        // stage A: 16 rows x 256 cols bf16 = 1024 u16x4 units, 512 thr x 2
        const unsigned short* prow = pooled + ((size_t)b * TOUT + j0) * ND;
        #pragma unroll
        for (int it = 0; it < 2; ++it) {
            const int u  = it * 512 + tid;
            const int m  = u >> 6;
            const int dd = (u & 63) * 4;
            *reinterpret_cast<u16x4*>(&a_lds[m * LDA + dd]) =
                *reinterpret_cast<const u16x4*>(prow + (size_t)u * 4);
        }
        __syncthreads();

        f32x4 acc[2];
        acc[0] = (f32x4){0.f, 0.f, 0.f, 0.f};
        acc[1] = (f32x4){0.f, 0.f, 0.f, 0.f};
        #pragma unroll
        for (int kk = 0; kk < 8; ++kk) {
            const int k0 = kk * 32 + kg * 8;
            bf16x8 af = *reinterpret_cast<const bf16x8*>(&a_lds[r * LDA + k0]);
            acc[0] = __builtin_amdgcn_mfma_f32_16x16x32_bf16(af, wreg[kk][0], acc[0], 0, 0, 0);
            acc[1] = __builtin_amdgcn_mfma_f32_16x16x32_bf16(af, wreg[kk][1], acc[1], 0, 0, 0);
        }

        // exact GELU; C/D layout (verified m89): col = lane&15, row = (lane>>4)*4 + q
        #pragma unroll
        for (int p = 0; p < 2; ++p) {
            const int col = wv * 32 + p * 16 + r;
            #pragma unroll
            for (int q = 0; q < 4; ++q)
                h_lds[(kg * 4 + q) * LDH + col] = gelu_exact(acc[p][q]);
        }
        __syncthreads();

        // LayerNorm over D: 16 rows, 8 waves -> 2 rows/wave, coalesced store
        #pragma unroll
        for (int i = 0; i < 2; ++i) {
            const int m = wv + i * 8;
            f32x4 v = *reinterpret_cast<const f32x4*>(&h_lds[m * LDH + lane * 4]);
            float s  = v.x + v.y + v.z + v.w;
            float sq = v.x * v.x + v.y * v.y + v.z * v.z + v.w * v.w;
            #pragma unroll
            for (int off = 32; off > 0; off >>= 1) {
                s  += __shfl_xor(s, off, 64);
                sq += __shfl_xor(sq, off, 64);
            }
            const float mean = s * (1.0f / 256.0f);
            const float var  = sq * (1.0f / 256.0f) - mean * mean;
            const float rs   = rsqrtf(var + 1e-5f);
            f32x4 o = (v - mean) * rs * g4 + b4;
            *reinterpret_cast<f32x4*>(&out[((size_t)(b * TOUT) + j0 + m) * ND + lane * 4]) = o;
        }
        __syncthreads();
    }
}

// Fallback (ws too small): monolithic fused kernel, dynamic pooling loop. Slow but correct.
__global__ __launch_bounds__(256, 4)
void fused_fallback(const float* __restrict__ mu,
                    const int* __restrict__ lens,
                    const int* __restrict__ olens,
                    const float* __restrict__ wf,
                    const float* __restrict__ gamma,
                    const float* __restrict__ beta,
                    float* __restrict__ out)
{
    __shared__ unsigned short a_lds[TILE_M * LDA];
    __shared__ float h_lds[TILE_M * LDH];

    const int b    = blockIdx.x;
    const int j0   = blockIdx.y * TILE_M;
    const int tid  = (int)threadIdx.x;
    const int lane = tid & 63;
    const int wv   = tid >> 6;
    const int L = lens[b];
    const int O = olens[b];

    for (int m = wv; m < TILE_M; m += 4) {
        const int j = j0 + m;
        f32x4 acc = {0.f, 0.f, 0.f, 0.f};
        if (j < O) {
            const int s = (j * L) / O;
            const int e = ((j + 1) * L + O - 1) / O;
            const float* src = mu + (size_t)(b * NT + s) * ND + lane * 4;
            for (int t = s; t < e; ++t) {
                acc += *reinterpret_cast<const f32x4*>(src);
                src += ND;
            }
            acc *= (1.0f / (float)(e - s));
        }
        u16x4 p;
        p.x = f2b(acc.x); p.y = f2b(acc.y); p.z = f2b(acc.z); p.w = f2b(acc.w);
        *reinterpret_cast<u16x4*>(&a_lds[m * LDA + lane * 4]) = p;
    }
    __syncthreads();

    const int r  = lane & 15;
    const int kg = lane >> 4;
    const int e0 = wv * 64;
    f32x4 acc[4];
    #pragma unroll
    for (int c = 0; c < 4; ++c) acc[c] = (f32x4){0.f, 0.f, 0.f, 0.f};
    #pragma unroll
    for (int kk = 0; kk < 8; ++kk) {
        const int k0 = kk * 32 + kg * 8;
        bf16x8 af = *reinterpret_cast<const bf16x8*>(&a_lds[r * LDA + k0]);
        #pragma unroll
        for (int ct = 0; ct < 4; ++ct) {
            const int e = e0 + ct * 16 + r;
            f32x4 w0 = *reinterpret_cast<const f32x4*>(&wf[e * ND + k0]);
            f32x4 w1 = *reinterpret_cast<const f32x4*>(&wf[e * ND + k0 + 4]);
            union { bf16x8 v; unsigned short u[8]; } cv;
            cv.u[0] = f2b(w0.x); cv.u[1] = f2b(w0.y);
            cv.u[2] = f2b(w0.z); cv.u[3] = f2b(w0.w);
            cv.u[4] = f2b(w1.x); cv.u[5] = f2b(w1.y);
            cv.u[6] = f2b(w1.z); cv.u[7] = f2b(w1.w);
            acc[ct] = __builtin_amdgcn_mfma_f32_16x16x32_bf16(af, cv.v, acc[ct], 0, 0, 0);
        }
    }
    #pragma unroll
    for (int ct = 0; ct < 4; ++ct) {
        const int col  = e0 + ct * 16 + r;
        const int row0 = kg * 4;
        #pragma unroll
        for (int q = 0; q < 4; ++q)
            h_lds[(row0 + q) * LDH + col] = gelu_exact(acc[ct][q]);
    }
    __syncthreads();
    const f32x4 g4 = *reinterpret_cast<const f32x4*>(&gamma[lane * 4]);
    const f32x4 b4 = *reinterpret_cast<const f32x4*>(&beta[lane * 4]);
    #pragma unroll
    for (int i = 0; i < 4; ++i) {
        const int m = wv + i * 4;
        f32x4 v = *reinterpret_cast<const f32x4*>(&h_lds[m * LDH + lane * 4]);
        float s  = v.x + v.y + v.z + v.w;
        float sq = v.x * v.x + v.y * v.y + v.z * v.z + v.w * v.w;
        #pragma unroll
        for (int off = 32; off > 0; off >>= 1) {
            s  += __shfl_xor(s, off, 64);
            sq += __shfl_xor(sq, off, 64);
        }
        const float mean = s * (1.0f / 256.0f);
        const float var  = sq * (1.0f / 256.0f) - mean * mean;
        const float rs   = rsqrtf(var + 1e-5f);
        f32x4 o = (v - mean) * rs * g4 + b4;
        *reinterpret_cast<f32x4*>(&out[((size_t)(b * TOUT) + j0 + m) * ND + lane * 4]) = o;
    }
}

extern "C" void kernel_launch(void* const* d_in, const int* in_sizes, int n_in,
                              void* d_out, int out_size, void* d_ws, size_t ws_size,
                              hipStream_t stream) {
    const float* mu    = (const float*)d_in[0];
    const int*   lens  = (const int*)d_in[1];
    const int*   olens = (const int*)d_in[2];
    const float* wf    = (const float*)d_in[3];
    const float* gamma = (const float*)d_in[4];
    const float* beta  = (const float*)d_in[5];
    float* out = (float*)d_out;

    const size_t wb_elems = (size_t)ND * ND;                       // 64 Ki bf16
    const size_t pooled_elems = (size_t)NB * TOUT * ND;            // 4 Mi bf16
    const size_t need = (wb_elems + pooled_elems) * sizeof(unsigned short);

    if (ws_size >= need) {
        unsigned short* wbF    = (unsigned short*)d_ws;
        unsigned short* pooled = wbF + wb_elems;
        pool_kernel<<<dim3(NB, TOUT / 4 + 1), dim3(256), 0, stream>>>(
            mu, lens, olens, wf, wbF, pooled);
        mm_kernel<<<dim3(NB, TOUT / BLK_J), dim3(512), 0, stream>>>(
            pooled, wbF, gamma, beta, out);
    } else {
        fused_fallback<<<dim3(NB, TOUT / TILE_M), dim3(256), 0, stream>>>(
            mu, lens, olens, wf, gamma, beta, out);
    }
}

// Round 8
// 26.306 us; speedup vs baseline: 2.2197x; 1.1006x over previous
//
#include <hip/hip_runtime.h>

#define NB 32
#define NT 2048
#define TOUT 512
#define ND 256
#define TILE_M 16
#define LDA 264   // ushort stride for pooled rows in LDS (256+8): 528B, 16B-aligned
#define LDH 264   // float stride for h rows

typedef __attribute__((ext_vector_type(4))) float f32x4;
typedef __attribute__((ext_vector_type(8))) short bf16x8;
typedef __attribute__((ext_vector_type(4))) unsigned short u16x4;

__device__ __forceinline__ unsigned short f2b(float f) {
    unsigned int u = __builtin_bit_cast(unsigned int, f);
    return (unsigned short)((u + 0x7FFFu + ((u >> 16) & 1u)) >> 16);  // RNE
}

__device__ __forceinline__ float gelu_exact(float x) {
    return 0.5f * x * (1.0f + erff(x * 0.70710678118654752440f));
}

template <int K>
__device__ __forceinline__ f32x4 sumK(const float* p) {
    f32x4 v[K];
    #pragma unroll
    for (int t = 0; t < K; ++t)
        v[t] = *reinterpret_cast<const f32x4*>(p + (size_t)t * ND);
    f32x4 s = v[0];
    #pragma unroll
    for (int t = 1; t < K; ++t) s += v[t];
    return s;
}

// W f32 -> bf16 FRAGMENT-MAJOR: wbF[((et*8+kk)*64 + lane)*8 + i] =
//   W[e = et*16 + (lane&15)][k = kk*32 + (lane>>4)*8 + i]
// so the fused kernel's B-fragment loads are lane-contiguous 1KB coalesced reads.
__global__ __launch_bounds__(512)
void cvt_w_kernel(const float* __restrict__ wf, unsigned short* __restrict__ wbF) {
    const int gid = blockIdx.x * 512 + (int)threadIdx.x;   // 8192 threads
    const int l   = gid & 63;
    const int kk  = (gid >> 6) & 7;
    const int et  = gid >> 9;                 // 0..15
    const int e   = et * 16 + (l & 15);
    const int k   = kk * 32 + (l >> 4) * 8;
    f32x4 a = *reinterpret_cast<const f32x4*>(wf + e * ND + k);
    f32x4 c = *reinterpret_cast<const f32x4*>(wf + e * ND + k + 4);
    u16x4 p0, p1;
    p0.x = f2b(a.x); p0.y = f2b(a.y); p0.z = f2b(a.z); p0.w = f2b(a.w);
    p1.x = f2b(c.x); p1.y = f2b(c.y); p1.z = f2b(c.z); p1.w = f2b(c.w);
    *reinterpret_cast<u16x4*>(wbF + (size_t)gid * 8)     = p0;
    *reinterpret_cast<u16x4*>(wbF + (size_t)gid * 8 + 4) = p1;
}

// Fused: inline ragged pool -> LDS(bf16) -> register-W MFMA -> GELU -> LN -> out.
// Grid (NB, TOUT/16) = 1024 blocks x 512 thr -> 2 blocks/CU.
__global__ __launch_bounds__(512, 2)
void fused_kernel(const float* __restrict__ mu,
                  const int* __restrict__ lens,
                  const int* __restrict__ olens,
                  const unsigned short* __restrict__ wbF,
                  const float* __restrict__ gamma,
                  const float* __restrict__ beta,
                  float* __restrict__ out)
{
    __shared__ unsigned short a_lds[TILE_M * LDA];  // pooled rows, bf16
    __shared__ float h_lds[TILE_M * LDH];           // post-GELU rows, f32

    const int b    = blockIdx.x;
    const int j0   = blockIdx.y * TILE_M;
    const int tid  = (int)threadIdx.x;
    const int lane = tid & 63;
    const int wv   = tid >> 6;     // 0..7, e-range [wv*32, wv*32+32)
    const int r    = lane & 15;
    const int kg   = lane >> 4;

    // ---- W fragments -> registers (once per block; coalesced 1KB loads) ----
    bf16x8 wreg[8][2];
    #pragma unroll
    for (int kk = 0; kk < 8; ++kk)
        #pragma unroll
        for (int p = 0; p < 2; ++p) {
            const int et = wv * 2 + p;
            wreg[kk][p] = *reinterpret_cast<const bf16x8*>(
                wbF + (size_t)((et * 8 + kk) * 64 + lane) * 8);
        }

    const int L = lens[b];
    const int O = olens[b];

    // ---- inline ragged pool: 2 rows per wave, exact-count unrolled loads ----
    #pragma unroll
    for (int i = 0; i < 2; ++i) {
        const int m = wv + i * 8;
        const int j = j0 + m;
        f32x4 s = {0.f, 0.f, 0.f, 0.f};
        if (j < O) {
            const int st  = (j * L) / O;
            const int en  = ((j + 1) * L + O - 1) / O;
            const int cnt = en - st;                 // wave-uniform, in [2, 9]
            const float* p = mu + (size_t)(b * NT + st) * ND + lane * 4;
            switch (cnt) {                           // uniform scalar branch
                case 2: s = sumK<2>(p); break;
                case 3: s = sumK<3>(p); break;
                case 4: s = sumK<4>(p); break;
                case 5: s = sumK<5>(p); break;
                case 6: s = sumK<6>(p); break;
                case 7: s = sumK<7>(p); break;
                case 8: s = sumK<8>(p); break;
                case 9: s = sumK<9>(p); break;
                default:
                    for (int t = 0; t < cnt; ++t)
                        s += *reinterpret_cast<const f32x4*>(p + (size_t)t * ND);
                    break;
            }
            s *= 1.0f / (float)cnt;
        }
        u16x4 q;
        q.x = f2b(s.x); q.y = f2b(s.y); q.z = f2b(s.z); q.w = f2b(s.w);
        *reinterpret_cast<u16x4*>(&a_lds[m * LDA + lane * 4]) = q;
    }
    __syncthreads();

    // ---- GEMM: 16 MFMA from LDS-A x register-W ----
    f32x4 acc[2];
    acc[0] = (f32x4){0.f, 0.f, 0.f, 0.f};
    acc[1] = (f32x4){0.f, 0.f, 0.f, 0.f};
    #pragma unroll
    for (int kk = 0; kk < 8; ++kk) {
        const int k0 = kk * 32 + kg * 8;
        bf16x8 af = *reinterpret_cast<const bf16x8*>(&a_lds[r * LDA + k0]);
        acc[0] = __builtin_amdgcn_mfma_f32_16x16x32_bf16(af, wreg[kk][0], acc[0], 0, 0, 0);
        acc[1] = __builtin_amdgcn_mfma_f32_16x16x32_bf16(af, wreg[kk][1], acc[1], 0, 0, 0);
    }

    // ---- exact GELU; C/D layout (verified m89): col = lane&15, row = (lane>>4)*4 + q
    #pragma unroll
    for (int p = 0; p < 2; ++p) {
        const int col = wv * 32 + p * 16 + r;
        #pragma unroll
        for (int q = 0; q < 4; ++q)
            h_lds[(kg * 4 + q) * LDH + col] = gelu_exact(acc[p][q]);
    }
    __syncthreads();

    // ---- LayerNorm over D: 2 rows/wave, coalesced store ----
    const f32x4 g4 = *reinterpret_cast<const f32x4*>(&gamma[lane * 4]);
    const f32x4 b4 = *reinterpret_cast<const f32x4*>(&beta[lane * 4]);
    #pragma unroll
    for (int i = 0; i < 2; ++i) {
        const int m = wv + i * 8;
        f32x4 v = *reinterpret_cast<const f32x4*>(&h_lds[m * LDH + lane * 4]);
        float s  = v.x + v.y + v.z + v.w;
        float sq = v.x * v.x + v.y * v.y + v.z * v.z + v.w * v.w;
        #pragma unroll
        for (int off = 32; off > 0; off >>= 1) {
            s  += __shfl_xor(s, off, 64);
            sq += __shfl_xor(sq, off, 64);
        }
        const float mean = s * (1.0f / 256.0f);
        const float var  = sq * (1.0f / 256.0f) - mean * mean;
        const float rs   = rsqrtf(var + 1e-5f);
        f32x4 o = (v - mean) * rs * g4 + b4;
        *reinterpret_cast<f32x4*>(&out[((size_t)(b * TOUT) + j0 + m) * ND + lane * 4]) = o;
    }
}

// Fallback (ws too small): monolithic fused kernel, dynamic pooling loop. Slow but correct.
__global__ __launch_bounds__(256, 4)
void fused_fallback(const float* __restrict__ mu,
                    const int* __restrict__ lens,
                    const int* __restrict__ olens,
                    const float* __restrict__ wf,
                    const float* __restrict__ gamma,
                    const float* __restrict__ beta,
                    float* __restrict__ out)
{
    __shared__ unsigned short a_lds[TILE_M * LDA];
    __shared__ float h_lds[TILE_M * LDH];

    const int b    = blockIdx.x;
    const int j0   = blockIdx.y * TILE_M;
    const int tid  = (int)threadIdx.x;
    const int lane = tid & 63;
    const int wv   = tid >> 6;
    const int L = lens[b];
    const int O = olens[b];

    for (int m = wv; m < TILE_M; m += 4) {
        const int j = j0 + m;
        f32x4 acc = {0.f, 0.f, 0.f, 0.f};
        if (j < O) {
            const int s = (j * L) / O;
            const int e = ((j + 1) * L + O - 1) / O;
            const float* src = mu + (size_t)(b * NT + s) * ND + lane * 4;
            for (int t = s; t < e; ++t) {
                acc += *reinterpret_cast<const f32x4*>(src);
                src += ND;
            }
            acc *= (1.0f / (float)(e - s));
        }
        u16x4 p;
        p.x = f2b(acc.x); p.y = f2b(acc.y); p.z = f2b(acc.z); p.w = f2b(acc.w);
        *reinterpret_cast<u16x4*>(&a_lds[m * LDA + lane * 4]) = p;
    }
    __syncthreads();

    const int r  = lane & 15;
    const int kg = lane >> 4;
    const int e0 = wv * 64;
    f32x4 acc[4];
    #pragma unroll
    for (int c = 0; c < 4; ++c) acc[c] = (f32x4){0.f, 0.f, 0.f, 0.f};
    #pragma unroll
    for (int kk = 0; kk < 8; ++kk) {
        const int k0 = kk * 32 + kg * 8;
        bf16x8 af = *reinterpret_cast<const bf16x8*>(&a_lds[r * LDA + k0]);
        #pragma unroll
        for (int ct = 0; ct < 4; ++ct) {
            const int e = e0 + ct * 16 + r;
            f32x4 w0 = *reinterpret_cast<const f32x4*>(&wf[e * ND + k0]);
            f32x4 w1 = *reinterpret_cast<const f32x4*>(&wf[e * ND + k0 + 4]);
            union { bf16x8 v; unsigned short u[8]; } cv;
            cv.u[0] = f2b(w0.x); cv.u[1] = f2b(w0.y);
            cv.u[2] = f2b(w0.z); cv.u[3] = f2b(w0.w);
            cv.u[4] = f2b(w1.x); cv.u[5] = f2b(w1.y);
            cv.u[6] = f2b(w1.z); cv.u[7] = f2b(w1.w);
            acc[ct] = __builtin_amdgcn_mfma_f32_16x16x32_bf16(af, cv.v, acc[ct], 0, 0, 0);
        }
    }
    #pragma unroll
    for (int ct = 0; ct < 4; ++ct) {
        const int col  = e0 + ct * 16 + r;
        const int row0 = kg * 4;
        #pragma unroll
        for (int q = 0; q < 4; ++q)
            h_lds[(row0 + q) * LDH + col] = gelu_exact(acc[ct][q]);
    }
    __syncthreads();
    const f32x4 g4 = *reinterpret_cast<const f32x4*>(&gamma[lane * 4]);
    const f32x4 b4 = *reinterpret_cast<const f32x4*>(&beta[lane * 4]);
    #pragma unroll
    for (int i = 0; i < 4; ++i) {
        const int m = wv + i * 4;
        f32x4 v = *reinterpret_cast<const f32x4*>(&h_lds[m * LDH + lane * 4]);
        float s  = v.x + v.y + v.z + v.w;
        float sq = v.x * v.x + v.y * v.y + v.z * v.z + v.w * v.w;
        #pragma unroll
        for (int off = 32; off > 0; off >>= 1) {
            s  += __shfl_xor(s, off, 64);
            sq += __shfl_xor(sq, off, 64);
        }
        const float mean = s * (1.0f / 256.0f);
        const float var  = sq * (1.0f / 256.0f) - mean * mean;
        const float rs   = rsqrtf(var + 1e-5f);
        f32x4 o = (v - mean) * rs * g4 + b4;
        *reinterpret_cast<f32x4*>(&out[((size_t)(b * TOUT) + j0 + m) * ND + lane * 4]) = o;
    }
}

extern "C" void kernel_launch(void* const* d_in, const int* in_sizes, int n_in,
                              void* d_out, int out_size, void* d_ws, size_t ws_size,
                              hipStream_t stream) {
    const float* mu    = (const float*)d_in[0];
    const int*   lens  = (const int*)d_in[1];
    const int*   olens = (const int*)d_in[2];
    const float* wf    = (const float*)d_in[3];
    const float* gamma = (const float*)d_in[4];
    const float* beta  = (const float*)d_in[5];
    float* out = (float*)d_out;

    const size_t need = (size_t)ND * ND * sizeof(unsigned short);  // 128 KB

    if (ws_size >= need) {
        unsigned short* wbF = (unsigned short*)d_ws;
        cvt_w_kernel<<<dim3(16), dim3(512), 0, stream>>>(wf, wbF);
        fused_kernel<<<dim3(NB, TOUT / TILE_M), dim3(512), 0, stream>>>(
            mu, lens, olens, wbF, gamma, beta, out);
    } else {
        fused_fallback<<<dim3(NB, TOUT / TILE_M), dim3(256), 0, stream>>>(
            mu, lens, olens, wf, gamma, beta, out);
    }
}